// Round 4
// baseline (520.613 us; speedup 1.0000x reference)
//
#include <hip/hip_runtime.h>

// WindowAttention fused, MI355X (gfx950).
// Shapes fixed: D=256, H=8, hd=32, W=2048, T=64, N=98304.
#define DD   256
#define HH   8
#define TT   64
#define WW   2048
#define WPB  8                 // windows per persistent block
#define NBLK (WW / WPB)        // 256 blocks = 1 per CU

typedef unsigned short u16;
typedef __attribute__((ext_vector_type(8))) __bf16 bf8_t;   // MFMA A/B frag (4 VGPR)
typedef __attribute__((ext_vector_type(4))) float  f32x4;   // MFMA C/D frag

typedef __attribute__((address_space(3))) unsigned int lds_u32;
typedef const __attribute__((address_space(1))) unsigned int glb_u32;

// XOR-swizzled [64 tok][256 col] u16 tile index (bank-conflict-free b128 col reads)
#define XSW(tok, col) ((tok) * 256 + ((col) ^ (((tok) & 7) << 3)))
// XOR-swizzled [256 vd][64 tok] u16 tile index
#define VSW(vd, tok)  ((vd) * 64 + ((tok) ^ (((vd) & 7) << 3)))

__device__ __forceinline__ u16 f2bf(float x) {
  union { float f; unsigned u; } c; c.f = x;
  unsigned r = c.u + 0x7FFFu + ((c.u >> 16) & 1u);   // RNE
  return (u16)(r >> 16);
}
__device__ __forceinline__ int pack2(float a, float b) {
  return (int)((unsigned)f2bf(a) | ((unsigned)f2bf(b) << 16));
}

__global__ void prep_weights(const float* __restrict__ inw, const float* __restrict__ outw,
                             u16* __restrict__ wq, u16* __restrict__ wo) {
  int i = blockIdx.x * blockDim.x + threadIdx.x;
  if (i < 768 * 256) wq[i] = f2bf(inw[i]);
  if (i < 256 * 256) wo[i] = f2bf(outw[i]);
}

__global__ void build_slots(const int* __restrict__ widx, const int* __restrict__ sidx,
                            int* __restrict__ wslots, int n) {
  int i = blockIdx.x * blockDim.x + threadIdx.x;
  if (i < n) wslots[widx[i] * TT + sidx[i]] = i;
}

// K1: packed bf16 conversion, pre-swizzled by in-window slot so that K2's linear
// global_load_lds DMA lands a bank-swizzled image in LDS (m173 pattern).
__global__ __launch_bounds__(256) void convert_x(
    const float* __restrict__ feat, const float* __restrict__ pos,
    const int* __restrict__ sidx,
    u16* __restrict__ xqk, u16* __restrict__ xv, int n) {
  int tid = blockIdx.x * 256 + threadIdx.x;
  int i = tid >> 3, seg = tid & 7;     // voxel row, 32-dim segment
  if (i >= n) return;
  int xm = (sidx[i] & 7) << 3;
  const float4* fp = (const float4*)(feat + (size_t)i * DD + seg * 32);
  const float4* pp = (const float4*)(pos  + (size_t)i * DD + seg * 32);
  float4 f[8], p[8];
#pragma unroll
  for (int j = 0; j < 8; ++j) { f[j] = fp[j]; p[j] = pp[j]; }
  const float* ff = (const float*)f;
  const float* pf = (const float*)p;
#pragma unroll
  for (int b = 0; b < 4; ++b) {
    union { u16 u[8]; bf8_t v; } rq, rv;
#pragma unroll
    for (int j = 0; j < 8; ++j) {
      float fv = ff[b * 8 + j];
      rq.u[j] = f2bf(fv + pf[b * 8 + j]);
      rv.u[j] = f2bf(fv);
    }
    int dst = i * DD + ((seg * 32 + b * 8) ^ xm);
    *(bf8_t*)&xqk[dst] = rq.v;
    *(bf8_t*)&xv[dst]  = rv.v;
  }
}

// DMA one 64x256 bf16 tile (32 KB) into LDS: 4 issues/wave x 8 waves x 1 KB.
// Per-lane global gather (row via slot table), wave-uniform LDS dest.
// Invalid slots redirect to row 0: finite real data; q-rows never stored,
// k masked by softmax, v weighted by p=0.
__device__ __forceinline__ void dma_tile(const u16* __restrict__ src,
                                         u16* lds, const int* tlrow,
                                         int h, int lane) {
#pragma unroll
  for (int j = 0; j < 4; ++j) {
    int tp = j * 8 + h;                      // token pair 0..31
    int tok = 2 * tp + (lane >> 5);
    int row = tlrow[tok];
    row = row < 0 ? 0 : row;
    const char* g = (const char*)src + (size_t)row * 512 + (lane & 31) * 16;
    __builtin_amdgcn_global_load_lds((glb_u32*)g, (lds_u32*)(lds + tp * 512), 16, 0, 0);
  }
}

// K2: persistent fused attention. 8 waves, wave h = head h.
// MFMA 16x16x32 bf16 layouts (HW-verified, carried from passing round-2 kernel):
//   A-frag: A[row=l&15][k=8*(l>>4)+j]   B-frag: B[k=8*(l>>4)+j][col=l&15]
//   C/D   : C[row=4*(l>>4)+reg][col=l&15]
// Barriers: 4/window. DMA for wi+1 issues mid-window (after QKV-pass reads),
// drains at next window's top vmcnt(0).
__global__ __launch_bounds__(512) void fused_attn(
    const u16* __restrict__ xqk, const u16* __restrict__ xv,
    const u16* __restrict__ wqkv,  // [768][256] bf16 (q 0-255, k 256-511, v 512-767)
    const u16* __restrict__ wout,  // [256][256] bf16
    const float* __restrict__ inb, const float* __restrict__ outb,
    const int* __restrict__ wslots, float* __restrict__ out) {

  __shared__ u16 Ax[TT * 256];     // Xqk tile (DMA, swizzled image)
  __shared__ u16 Bx[TT * 256];     // Xv tile (DMA)
  __shared__ u16 Ck[TT * 256];     // k [64][256] -> v^T [256][64]
  __shared__ u16 Dq[TT * 256];     // q [64][256] -> aout [64][256]
  __shared__ int tl2[2][TT];       // slot -> voxel row, double-buffered

  const int t    = threadIdx.x;
  const int h    = t >> 6;
  const int lane = t & 63;
  const int g    = lane >> 4;
  const int l16  = lane & 15;
  const int base = blockIdx.x * WPB;

  const f32x4 zf = {0.f, 0.f, 0.f, 0.f};

  // prologue: slot table + DMA for window 0
  if (t < TT) tl2[0][t] = wslots[base * TT + t];
  __syncthreads();
  dma_tile(xqk, Ax, tl2[0], h, lane);
  dma_tile(xv,  Bx, tl2[0], h, lane);

#pragma unroll 1
  for (int wi = 0; wi < WPB; ++wi) {
    const int cb = wi & 1, nb = cb ^ 1;

    asm volatile("s_waitcnt vmcnt(0)" ::: "memory");
    __syncthreads();                                   // B0: tiles ready, C/D free

    // prefetch next window's slot table (in flight across QKV pass)
    int tln = 0;
    if (wi + 1 < WPB) tln = wslots[(base + wi + 1) * TT + (t & 63)];

    // ---- v-pass: va = Wv · Xv^T (C rows = vdim, cols = tok) ----
    f32x4 va[2][4];
#pragma unroll
    for (int md = 0; md < 2; ++md)
#pragma unroll
      for (int nt = 0; nt < 4; ++nt) va[md][nt] = zf;

    for (int kc = 0; kc < 4; ++kc) {
      bf8_t bx[4][2];
#pragma unroll
      for (int nt = 0; nt < 4; ++nt)
#pragma unroll
        for (int ks = 0; ks < 2; ++ks)
          bx[nt][ks] = *(const bf8_t*)&Bx[XSW(nt * 16 + l16, kc * 64 + ks * 32 + g * 8)];
#pragma unroll
      for (int ks = 0; ks < 2; ++ks) {
        const int kb = kc * 64 + ks * 32 + g * 8;
#pragma unroll
        for (int md = 0; md < 2; ++md) {
          bf8_t awv = *(const bf8_t*)(wqkv + (size_t)(512 + h * 32 + md * 16 + l16) * DD + kb);
#pragma unroll
          for (int nt = 0; nt < 4; ++nt)
            va[md][nt] = __builtin_amdgcn_mfma_f32_16x16x32_bf16(awv, bx[nt][ks], va[md][nt], 0, 0, 0);
        }
      }
    }

    // ---- qk-pass: qa,ka = Xqk · W^T ----
    f32x4 qa[4][2], ka[4][2];
#pragma unroll
    for (int mt = 0; mt < 4; ++mt)
#pragma unroll
      for (int nt = 0; nt < 2; ++nt) { qa[mt][nt] = zf; ka[mt][nt] = zf; }

    for (int kc = 0; kc < 4; ++kc) {
      bf8_t ax[4][2];
#pragma unroll
      for (int mt = 0; mt < 4; ++mt)
#pragma unroll
        for (int ks = 0; ks < 2; ++ks)
          ax[mt][ks] = *(const bf8_t*)&Ax[XSW(mt * 16 + l16, kc * 64 + ks * 32 + g * 8)];
#pragma unroll
      for (int ks = 0; ks < 2; ++ks) {
        const int kb = kc * 64 + ks * 32 + g * 8;
#pragma unroll
        for (int nt = 0; nt < 2; ++nt) {
          bf8_t bwq = *(const bf8_t*)(wqkv + (size_t)(h * 32 + nt * 16 + l16) * DD + kb);
#pragma unroll
          for (int mt = 0; mt < 4; ++mt)
            qa[mt][nt] = __builtin_amdgcn_mfma_f32_16x16x32_bf16(ax[mt][ks], bwq, qa[mt][nt], 0, 0, 0);
          bf8_t bwk = *(const bf8_t*)(wqkv + (size_t)(256 + h * 32 + nt * 16 + l16) * DD + kb);
#pragma unroll
          for (int mt = 0; mt < 4; ++mt)
            ka[mt][nt] = __builtin_amdgcn_mfma_f32_16x16x32_bf16(ax[mt][ks], bwk, ka[mt][nt], 0, 0, 0);
        }
      }
    }

    // ---- q -> Dq, k -> Ck (+biases); wave-private head columns ----
#pragma unroll
    for (int nt = 0; nt < 2; ++nt) {
      float bq = inb[h * 32 + nt * 16 + l16];
      float bk = inb[256 + h * 32 + nt * 16 + l16];
#pragma unroll
      for (int mt = 0; mt < 4; ++mt)
#pragma unroll
        for (int r = 0; r < 4; ++r) {
          int tok = mt * 16 + 4 * g + r;
          int col = h * 32 + nt * 16 + l16;
          Dq[XSW(tok, col)] = f2bf(qa[mt][nt][r] + bq);
          Ck[XSW(tok, col)] = f2bf(ka[mt][nt][r] + bk);
        }
    }
    if (t < TT && wi + 1 < WPB) tl2[nb][t] = tln;
    __syncthreads();                                   // B1: A/B reads done; k,q,tl visible

    // ---- DMA next window into Ax/Bx (hidden under attention + out_proj) ----
    if (wi + 1 < WPB) {
      dma_tile(xqk, Ax, tl2[nb], h, lane);
      dma_tile(xv,  Bx, tl2[nb], h, lane);
    }

    // ---- S^T = K · Q^T (reads own-wave head columns of Ck/Dq) ----
    bf8_t akf[4], bqf[4];
#pragma unroll
    for (int mt = 0; mt < 4; ++mt) akf[mt] = *(const bf8_t*)&Ck[XSW(mt * 16 + l16, h * 32 + g * 8)];
#pragma unroll
    for (int nt = 0; nt < 4; ++nt) bqf[nt] = *(const bf8_t*)&Dq[XSW(nt * 16 + l16, h * 32 + g * 8)];

    f32x4 sa[4][4];
#pragma unroll
    for (int mt = 0; mt < 4; ++mt)
#pragma unroll
      for (int nt = 0; nt < 4; ++nt)
        sa[mt][nt] = __builtin_amdgcn_mfma_f32_16x16x32_bf16(akf[mt], bqf[nt], zf, 0, 0, 0);

    __syncthreads();                                   // B2: all k reads done -> Ck reusable as v^T

    // ---- v^T (+bias) -> Ck (wave-private rows) ----
#pragma unroll
    for (int md = 0; md < 2; ++md)
#pragma unroll
      for (int r = 0; r < 4; ++r) {
        float bv = inb[512 + h * 32 + md * 16 + 4 * g + r];
#pragma unroll
        for (int nt = 0; nt < 4; ++nt)
          Ck[VSW(h * 32 + md * 16 + 4 * g + r, nt * 16 + l16)] = f2bf(va[md][nt][r] + bv);
      }

    // ---- masked softmax along tok (q-row lane-local across 4 groups) ----
    bool vm[4][4];
#pragma unroll
    for (int mt = 0; mt < 4; ++mt)
#pragma unroll
      for (int r = 0; r < 4; ++r) vm[mt][r] = (tl2[cb][mt * 16 + 4 * g + r] >= 0);

    const float scale = 0.17677669529663687f;  // 1/sqrt(32)
    int pk[4][4][2];
#pragma unroll
    for (int nt = 0; nt < 4; ++nt) {
      float sv[4][4];
      float m = -3e38f;
#pragma unroll
      for (int mt = 0; mt < 4; ++mt)
#pragma unroll
        for (int r = 0; r < 4; ++r) {
          float s = vm[mt][r] ? sa[mt][nt][r] * scale : -3e38f;
          sv[mt][r] = s;
          m = fmaxf(m, s);
        }
      m = fmaxf(m, __shfl_xor(m, 16, 64));
      m = fmaxf(m, __shfl_xor(m, 32, 64));
      float sum = 0.f;
#pragma unroll
      for (int mt = 0; mt < 4; ++mt)
#pragma unroll
        for (int r = 0; r < 4; ++r) {
          float p = vm[mt][r] ? __expf(sv[mt][r] - m) : 0.f;
          sv[mt][r] = p;
          sum += p;
        }
      sum += __shfl_xor(sum, 16, 64);
      sum += __shfl_xor(sum, 32, 64);
      float inv = sum > 0.f ? 1.f / sum : 0.f;
#pragma unroll
      for (int mt = 0; mt < 4; ++mt)
#pragma unroll
        for (int rp = 0; rp < 2; ++rp)
          pk[mt][nt][rp] = pack2(sv[mt][2 * rp] * inv, sv[mt][2 * rp + 1] * inv);
    }

    // ---- PV: out^T = V^T · P^T ----
    bf8_t avf[2][2];
#pragma unroll
    for (int md = 0; md < 2; ++md)
#pragma unroll
      for (int kk = 0; kk < 2; ++kk)
        avf[md][kk] = *(const bf8_t*)&Ck[VSW(h * 32 + md * 16 + l16, kk * 32 + g * 8)];

    f32x4 oa[2][4];
#pragma unroll
    for (int md = 0; md < 2; ++md)
#pragma unroll
      for (int nt = 0; nt < 4; ++nt) oa[md][nt] = zf;

#pragma unroll
    for (int kk = 0; kk < 2; ++kk) {
#pragma unroll
      for (int nt = 0; nt < 4; ++nt) {
        union { int wd[4]; bf8_t v; } bu;
#pragma unroll
        for (int wd = 0; wd < 4; ++wd) {
          int src = l16 + 16 * (2 * (g & 1) + (wd >> 1));
          int lo = __shfl(pk[2 * kk + 0][nt][wd & 1], src, 64);
          int hi = __shfl(pk[2 * kk + 1][nt][wd & 1], src, 64);
          bu.wd[wd] = (g & 2) ? hi : lo;
        }
#pragma unroll
        for (int md = 0; md < 2; ++md)
          oa[md][nt] = __builtin_amdgcn_mfma_f32_16x16x32_bf16(avf[md][kk], bu.v, oa[md][nt], 0, 0, 0);
      }
    }

    // ---- aout -> Dq (own head cols; q already consumed by own wave) ----
#pragma unroll
    for (int md = 0; md < 2; ++md)
#pragma unroll
      for (int nt = 0; nt < 4; ++nt) {
        int w0 = pack2(oa[md][nt][0], oa[md][nt][1]);
        int w1 = pack2(oa[md][nt][2], oa[md][nt][3]);
        *(int2*)&Dq[XSW(nt * 16 + l16, h * 32 + md * 16 + 4 * g)] = make_int2(w0, w1);
      }
    __syncthreads();                                   // B3: aout all-visible

    // ---- out_proj + store ----
    f32x4 fa[4][2];
#pragma unroll
    for (int mt = 0; mt < 4; ++mt)
#pragma unroll
      for (int nt = 0; nt < 2; ++nt) fa[mt][nt] = zf;

#pragma unroll
    for (int kk = 0; kk < 8; ++kk) {
      bf8_t aa[4];
#pragma unroll
      for (int mt = 0; mt < 4; ++mt)
        aa[mt] = *(const bf8_t*)&Dq[XSW(mt * 16 + l16, kk * 32 + g * 8)];
#pragma unroll
      for (int nt = 0; nt < 2; ++nt) {
        bf8_t bw = *(const bf8_t*)(wout + (size_t)(h * 32 + nt * 16 + l16) * DD + kk * 32 + g * 8);
#pragma unroll
        for (int mt = 0; mt < 4; ++mt)
          fa[mt][nt] = __builtin_amdgcn_mfma_f32_16x16x32_bf16(aa[mt], bw, fa[mt][nt], 0, 0, 0);
      }
    }

#pragma unroll
    for (int nt = 0; nt < 2; ++nt) {
      float ob = outb[h * 32 + nt * 16 + l16];
#pragma unroll
      for (int mt = 0; mt < 4; ++mt)
#pragma unroll
        for (int r = 0; r < 4; ++r) {
          int tok = mt * 16 + 4 * g + r;
          int row = tl2[cb][tok];
          if (row >= 0)
            out[(size_t)row * DD + h * 32 + nt * 16 + l16] = fa[mt][nt][r] + ob;
        }
    }
    // next iteration's B0 (vmcnt(0)+barrier) orders Dq reads vs next q writes
  }
}

extern "C" void kernel_launch(void* const* d_in, const int* in_sizes, int n_in,
                              void* d_out, int out_size, void* d_ws, size_t ws_size,
                              hipStream_t stream) {
  (void)n_in; (void)out_size; (void)ws_size;
  const float* feat = (const float*)d_in[0];
  const float* pos  = (const float*)d_in[1];
  const float* inw  = (const float*)d_in[2];
  const float* inb  = (const float*)d_in[3];
  const float* outw = (const float*)d_in[4];
  const float* outb = (const float*)d_in[5];
  const int*   widx = (const int*)d_in[6];
  const int*   sidx = (const int*)d_in[7];
  const int N = in_sizes[0] / DD;

  char* ws = (char*)d_ws;
  u16* wqkv   = (u16*)ws;                               // 393216 B
  u16* wout   = (u16*)(ws + 393216);                    // 131072 B
  int* wslots = (int*)(ws + 393216 + 131072);           // 524288 B
  u16* xqk    = (u16*)(ws + 1048576);                   // N*512 B
  u16* xv     = (u16*)(ws + 1048576 + (size_t)N * 512); // N*512 B

  hipMemsetAsync(wslots, 0xFF, WW * TT * sizeof(int), stream);
  prep_weights<<<768, 256, 0, stream>>>(inw, outw, wqkv, wout);
  build_slots<<<(N + 255) / 256, 256, 0, stream>>>(widx, sidx, wslots, N);
  convert_x<<<(N * 8 + 255) / 256, 256, 0, stream>>>(feat, pos, sidx, xqk, xv, N);
  fused_attn<<<NBLK, 512, 0, stream>>>(xqk, xv, wqkv, wout, inb, outb, wslots, (float*)d_out);
}

// Round 5
// 351.493 us; speedup vs baseline: 1.4811x; 1.4811x over previous
//
#include <hip/hip_runtime.h>

// WindowAttention, MI355X (gfx950). Split pipeline:
//   prep_weights -> build_slots -> qkv_gemm (K1) -> attn_out (K2)
// Shapes fixed: D=256, H=8, hd=32, W=2048, T=64, N=98304.
#define DD 256
#define TT 64
#define WW 2048

typedef unsigned short u16;
typedef __attribute__((ext_vector_type(8))) __bf16 bf8_t;   // MFMA A/B frag (4 VGPR)
typedef __attribute__((ext_vector_type(4))) float  f32x4;   // MFMA C/D frag

// XOR-swizzled [64 tok][256 col] u16 tile index (bank-conflict-free b128 col reads)
#define XSW(tok, col) ((tok) * 256 + ((col) ^ (((tok) & 7) << 3)))

__device__ __forceinline__ u16 f2bf(float x) {
  union { float f; unsigned u; } c; c.f = x;
  unsigned r = c.u + 0x7FFFu + ((c.u >> 16) & 1u);   // RNE
  return (u16)(r >> 16);
}
__device__ __forceinline__ int pack2(float a, float b) {
  return (int)((unsigned)f2bf(a) | ((unsigned)f2bf(b) << 16));
}

__global__ void prep_weights(const float* __restrict__ inw, const float* __restrict__ outw,
                             u16* __restrict__ wq, u16* __restrict__ wo) {
  int i = blockIdx.x * blockDim.x + threadIdx.x;
  if (i < 768 * 256) wq[i] = f2bf(inw[i]);
  if (i < 256 * 256) wo[i] = f2bf(outw[i]);
}

__global__ void build_slots(const int* __restrict__ widx, const int* __restrict__ sidx,
                            int* __restrict__ wslots, int n) {
  int i = blockIdx.x * blockDim.x + threadIdx.x;
  if (i < n) wslots[widx[i] * TT + sidx[i]] = i;
}

// ---------------- K1: QKV projection GEMM ----------------
// grid (N/64, 3): x = 64-voxel M-tile, y = pass (0=q, 1=k, 2=v).
// Pass 0/1: C[vox][outdim] = bf16(feat+pos) @ W^T  -> qc/kc [N][256] bf16.
// Pass 2:   C[vdim][vox]   = Wv @ bf16(feat)^T     -> vt [w][vdim][64slots] bf16
//           (transposed, window-padded; pad slots never written -> finite garbage,
//            always multiplied by exactly-0 attention weights in K2).
// MFMA 16x16x32 bf16 layouts (HW-verified across rounds 1-4):
//   A-frag: A[row=l&15][k=8*(l>>4)+j]   B-frag: B[k=8*(l>>4)+j][col=l&15]
//   C/D   : C[row=4*(l>>4)+reg][col=l&15]
__global__ __launch_bounds__(256, 4) void qkv_gemm(
    const float* __restrict__ feat, const float* __restrict__ pos,
    const u16* __restrict__ wqkv, const float* __restrict__ inb,
    const int* __restrict__ widx, const int* __restrict__ sidx,
    u16* __restrict__ qc, u16* __restrict__ kc, u16* __restrict__ vt) {

  __shared__ u16 xb[TT * 72];      // x chunk [64 vox][64 k], stride 144 B
  __shared__ u16 cb[TT * 264];     // C transpose buffer [64 vox][256+pad]

  const int t    = threadIdx.x;
  const int wv   = t >> 6;         // wave 0..3 -> 64-col slice
  const int lane = t & 63;
  const int g    = lane >> 4;
  const int l16  = lane & 15;
  const int m0   = blockIdx.x * 64;
  const int p    = blockIdx.y;     // 0=q 1=k 2=v

  const int svox = t >> 2;         // staging: voxel
  const int sseg = t & 3;          // 16-dim segment within 64-dim chunk

  const f32x4 zf = {0.f, 0.f, 0.f, 0.f};
  f32x4 acc[4][4];
#pragma unroll
  for (int mt = 0; mt < 4; ++mt)
#pragma unroll
    for (int nt = 0; nt < 4; ++nt) acc[mt][nt] = zf;

  for (int kc_ = 0; kc_ < 4; ++kc_) {
    // ---- stage xb = bf16(x[m0+svox][kc_*64 + sseg*16 .. +15]) ----
    {
      const float4* fp = (const float4*)(feat + (size_t)(m0 + svox) * DD + kc_ * 64 + sseg * 16);
      float4 f[4];
#pragma unroll
      for (int j = 0; j < 4; ++j) f[j] = fp[j];
      float fr[16];
#pragma unroll
      for (int j = 0; j < 16; ++j) fr[j] = ((const float*)f)[j];
      if (p < 2) {
        const float4* pp = (const float4*)(pos + (size_t)(m0 + svox) * DD + kc_ * 64 + sseg * 16);
        float4 q[4];
#pragma unroll
        for (int j = 0; j < 4; ++j) q[j] = pp[j];
#pragma unroll
        for (int j = 0; j < 16; ++j) fr[j] += ((const float*)q)[j];
      }
#pragma unroll
      for (int c = 0; c < 2; ++c) {
        union { u16 u[8]; bf8_t v; } r;
#pragma unroll
        for (int j = 0; j < 8; ++j) r.u[j] = f2bf(fr[c * 8 + j]);
        *(bf8_t*)&xb[svox * 72 + sseg * 16 + c * 8] = r.v;
      }
    }
    __syncthreads();

    if (p < 2) {
      // A = x rows, B = W rows (outdim-major)
      bf8_t ax[4][2];
#pragma unroll
      for (int mt = 0; mt < 4; ++mt)
#pragma unroll
        for (int ks = 0; ks < 2; ++ks)
          ax[mt][ks] = *(const bf8_t*)&xb[(mt * 16 + l16) * 72 + ks * 32 + g * 8];
#pragma unroll
      for (int ks = 0; ks < 2; ++ks) {
        const int kb = kc_ * 64 + ks * 32 + g * 8;
#pragma unroll
        for (int nt = 0; nt < 4; ++nt) {
          bf8_t bw = *(const bf8_t*)(wqkv + (size_t)(p * 256 + wv * 64 + nt * 16 + l16) * DD + kb);
#pragma unroll
          for (int mt = 0; mt < 4; ++mt)
            acc[mt][nt] = __builtin_amdgcn_mfma_f32_16x16x32_bf16(ax[mt][ks], bw, acc[mt][nt], 0, 0, 0);
        }
      }
    } else {
      // A = Wv rows (vdim-major), B = x^T (cols = vox)
      bf8_t bx[4][2];
#pragma unroll
      for (int nt = 0; nt < 4; ++nt)
#pragma unroll
        for (int ks = 0; ks < 2; ++ks)
          bx[nt][ks] = *(const bf8_t*)&xb[(nt * 16 + l16) * 72 + ks * 32 + g * 8];
#pragma unroll
      for (int ks = 0; ks < 2; ++ks) {
        const int kb = kc_ * 64 + ks * 32 + g * 8;
#pragma unroll
        for (int mt = 0; mt < 4; ++mt) {
          bf8_t aw = *(const bf8_t*)(wqkv + (size_t)(512 + wv * 64 + mt * 16 + l16) * DD + kb);
#pragma unroll
          for (int nt = 0; nt < 4; ++nt)
            acc[mt][nt] = __builtin_amdgcn_mfma_f32_16x16x32_bf16(aw, bx[nt][ks], acc[mt][nt], 0, 0, 0);
        }
      }
    }
    __syncthreads();
  }

  if (p < 2) {
    // bias -> cb (vox-major) -> coalesced copy to qc/kc
#pragma unroll
    for (int nt = 0; nt < 4; ++nt) {
      float b = inb[p * 256 + wv * 64 + nt * 16 + l16];
#pragma unroll
      for (int mt = 0; mt < 4; ++mt)
#pragma unroll
        for (int r = 0; r < 4; ++r)
          cb[(mt * 16 + 4 * g + r) * 264 + wv * 64 + nt * 16 + l16] = f2bf(acc[mt][nt][r] + b);
    }
    __syncthreads();
    u16* dst = p ? kc : qc;
#pragma unroll
    for (int it = 0; it < 8; ++it) {
      int i = it * 256 + t;
      int row = i >> 5, c8 = (i & 31) * 8;
      *(bf8_t*)&dst[(size_t)(m0 + row) * DD + c8] = *(const bf8_t*)&cb[row * 264 + c8];
    }
  } else {
    // direct transposed scatter: vt[w][vdim][slot]
#pragma unroll
    for (int nt = 0; nt < 4; ++nt) {
      int vx = m0 + nt * 16 + l16;
      size_t bw_ = (size_t)widx[vx] * (DD * TT) + sidx[vx];
#pragma unroll
      for (int mt = 0; mt < 4; ++mt)
#pragma unroll
        for (int r = 0; r < 4; ++r) {
          int vd = wv * 64 + mt * 16 + 4 * g + r;
          vt[bw_ + (size_t)vd * TT] = f2bf(acc[mt][nt][r] + inb[512 + vd]);
        }
    }
  }
}

// ---------------- K2: attention + out_proj ----------------
// grid (2048): block = window, 256 thr = 4 waves, wave wv does heads {2wv, 2wv+1}.
// k/q MFMA frags gathered directly from global (16B/lane, slot-table rows);
// vt frags contiguous b128. Only 2 barriers.
__global__ __launch_bounds__(256, 4) void attn_out(
    const u16* __restrict__ qc, const u16* __restrict__ kc, const u16* __restrict__ vt,
    const u16* __restrict__ wout, const float* __restrict__ outb,
    const int* __restrict__ wslots, float* __restrict__ out) {

  __shared__ int tl[TT];
  __shared__ u16 ab[TT * 256];     // aout [64 tok][256], XSW-swizzled

  const int t    = threadIdx.x;
  const int wv   = t >> 6;
  const int lane = t & 63;
  const int g    = lane >> 4;
  const int l16  = lane & 15;
  const int w    = blockIdx.x;

  if (t < TT) tl[t] = wslots[w * TT + t];
  __syncthreads();

  const f32x4 zf = {0.f, 0.f, 0.f, 0.f};

  // key/query validity masks (head-independent)
  bool vm[4][4];
#pragma unroll
  for (int mt = 0; mt < 4; ++mt)
#pragma unroll
    for (int r = 0; r < 4; ++r) vm[mt][r] = (tl[mt * 16 + 4 * g + r] >= 0);

#pragma unroll 1
  for (int hh = 0; hh < 2; ++hh) {
    const int h = wv * 2 + hh;

    // ---- S^T = K · Q^T : frags straight from global ----
    bf8_t akf[4], bqf[4];
#pragma unroll
    for (int mt = 0; mt < 4; ++mt) {
      int row = tl[mt * 16 + l16]; row = row < 0 ? 0 : row;
      akf[mt] = *(const bf8_t*)&kc[(size_t)row * DD + h * 32 + g * 8];
    }
#pragma unroll
    for (int nt = 0; nt < 4; ++nt) {
      int row = tl[nt * 16 + l16]; row = row < 0 ? 0 : row;
      bqf[nt] = *(const bf8_t*)&qc[(size_t)row * DD + h * 32 + g * 8];
    }

    f32x4 sa[4][4];
#pragma unroll
    for (int mt = 0; mt < 4; ++mt)
#pragma unroll
      for (int nt = 0; nt < 4; ++nt)
        sa[mt][nt] = __builtin_amdgcn_mfma_f32_16x16x32_bf16(akf[mt], bqf[nt], zf, 0, 0, 0);

    // ---- masked softmax along tok (q-row lane-local across 4 groups) ----
    const float scale = 0.17677669529663687f;  // 1/sqrt(32)
    int pk[4][4][2];
#pragma unroll
    for (int nt = 0; nt < 4; ++nt) {
      float sv[4][4];
      float m = -3e38f;
#pragma unroll
      for (int mt = 0; mt < 4; ++mt)
#pragma unroll
        for (int r = 0; r < 4; ++r) {
          float s = vm[mt][r] ? sa[mt][nt][r] * scale : -3e38f;
          sv[mt][r] = s;
          m = fmaxf(m, s);
        }
      m = fmaxf(m, __shfl_xor(m, 16, 64));
      m = fmaxf(m, __shfl_xor(m, 32, 64));
      float sum = 0.f;
#pragma unroll
      for (int mt = 0; mt < 4; ++mt)
#pragma unroll
        for (int r = 0; r < 4; ++r) {
          float pv = vm[mt][r] ? __expf(sv[mt][r] - m) : 0.f;
          sv[mt][r] = pv;
          sum += pv;
        }
      sum += __shfl_xor(sum, 16, 64);
      sum += __shfl_xor(sum, 32, 64);
      float inv = sum > 0.f ? 1.f / sum : 0.f;
#pragma unroll
      for (int mt = 0; mt < 4; ++mt)
#pragma unroll
        for (int rp = 0; rp < 2; ++rp)
          pk[mt][nt][rp] = pack2(sv[mt][2 * rp] * inv, sv[mt][2 * rp + 1] * inv);
    }

    // ---- PV: out^T = V^T · P^T ; vt frags contiguous ----
    bf8_t avf[2][2];
#pragma unroll
    for (int md = 0; md < 2; ++md)
#pragma unroll
      for (int kk = 0; kk < 2; ++kk)
        avf[md][kk] = *(const bf8_t*)&vt[(size_t)w * (DD * TT) +
                                        (size_t)(h * 32 + md * 16 + l16) * TT + kk * 32 + g * 8];

    f32x4 oa[2][4];
#pragma unroll
    for (int md = 0; md < 2; ++md)
#pragma unroll
      for (int nt = 0; nt < 4; ++nt) oa[md][nt] = zf;

#pragma unroll
    for (int kk = 0; kk < 2; ++kk) {
#pragma unroll
      for (int nt = 0; nt < 4; ++nt) {
        union { int wd[4]; bf8_t v; } bu;
#pragma unroll
        for (int wd = 0; wd < 4; ++wd) {
          int src = l16 + 16 * (2 * (g & 1) + (wd >> 1));
          int lo = __shfl(pk[2 * kk + 0][nt][wd & 1], src, 64);
          int hi = __shfl(pk[2 * kk + 1][nt][wd & 1], src, 64);
          bu.wd[wd] = (g & 2) ? hi : lo;
        }
#pragma unroll
        for (int md = 0; md < 2; ++md)
          oa[md][nt] = __builtin_amdgcn_mfma_f32_16x16x32_bf16(avf[md][kk], bu.v, oa[md][nt], 0, 0, 0);
      }
    }

    // ---- aout -> ab (own head's 32-col slice; wave-private) ----
#pragma unroll
    for (int md = 0; md < 2; ++md)
#pragma unroll
      for (int nt = 0; nt < 4; ++nt) {
        int w0 = pack2(oa[md][nt][0], oa[md][nt][1]);
        int w1 = pack2(oa[md][nt][2], oa[md][nt][3]);
        *(int2*)&ab[XSW(nt * 16 + l16, h * 32 + md * 16 + 4 * g)] = make_int2(w0, w1);
      }
  }
  __syncthreads();     // aout all-visible

  // ---- out_proj: wave wv covers cols wv*64..wv*64+63 ----
  f32x4 fa[4][4];
#pragma unroll
  for (int mt = 0; mt < 4; ++mt)
#pragma unroll
    for (int nt = 0; nt < 4; ++nt) fa[mt][nt] = zf;

#pragma unroll
  for (int kk = 0; kk < 8; ++kk) {
    bf8_t aa[4];
#pragma unroll
    for (int mt = 0; mt < 4; ++mt)
      aa[mt] = *(const bf8_t*)&ab[XSW(mt * 16 + l16, kk * 32 + g * 8)];
#pragma unroll
    for (int nt = 0; nt < 4; ++nt) {
      bf8_t bw = *(const bf8_t*)(wout + (size_t)(wv * 64 + nt * 16 + l16) * DD + kk * 32 + g * 8);
#pragma unroll
      for (int mt = 0; mt < 4; ++mt)
        fa[mt][nt] = __builtin_amdgcn_mfma_f32_16x16x32_bf16(aa[mt], bw, fa[mt][nt], 0, 0, 0);
    }
  }

#pragma unroll
  for (int nt = 0; nt < 4; ++nt) {
    float ob = outb[wv * 64 + nt * 16 + l16];
#pragma unroll
    for (int mt = 0; mt < 4; ++mt)
#pragma unroll
      for (int r = 0; r < 4; ++r) {
        int row = tl[mt * 16 + 4 * g + r];
        if (row >= 0)
          out[(size_t)row * DD + wv * 64 + nt * 16 + l16] = fa[mt][nt][r] + ob;
      }
  }
}

extern "C" void kernel_launch(void* const* d_in, const int* in_sizes, int n_in,
                              void* d_out, int out_size, void* d_ws, size_t ws_size,
                              hipStream_t stream) {
  (void)n_in; (void)out_size; (void)ws_size;
  const float* feat = (const float*)d_in[0];
  const float* pos  = (const float*)d_in[1];
  const float* inw  = (const float*)d_in[2];
  const float* inb  = (const float*)d_in[3];
  const float* outw = (const float*)d_in[4];
  const float* outb = (const float*)d_in[5];
  const int*   widx = (const int*)d_in[6];
  const int*   sidx = (const int*)d_in[7];
  const int N = in_sizes[0] / DD;

  char* ws = (char*)d_ws;
  u16* wqkv   = (u16*)ws;                                    // 393216 B
  u16* wout   = (u16*)(ws + 393216);                         // 131072 B
  int* wslots = (int*)(ws + 393216 + 131072);                // 524288 B
  size_t off  = 1048576;
  u16* qc = (u16*)(ws + off); off += (size_t)N * DD * 2;     // 50.3 MB
  u16* kc = (u16*)(ws + off); off += (size_t)N * DD * 2;     // 50.3 MB
  u16* vt = (u16*)(ws + off);                                // 67.1 MB

  hipMemsetAsync(wslots, 0xFF, WW * TT * sizeof(int), stream);
  prep_weights<<<768, 256, 0, stream>>>(inw, outw, wqkv, wout);
  build_slots<<<(N + 255) / 256, 256, 0, stream>>>(widx, sidx, wslots, N);
  qkv_gemm<<<dim3(N / 64, 3), 256, 0, stream>>>(feat, pos, wqkv, inb, widx, sidx, qc, kc, vt);
  attn_out<<<WW, 256, 0, stream>>>(qc, kc, vt, wout, outb, wslots, (float*)d_out);
}

// Round 7
// 311.971 us; speedup vs baseline: 1.6688x; 1.1267x over previous
//
#include <hip/hip_runtime.h>

// WindowAttention, MI355X (gfx950). Pipeline:
//   prep_weights (frag-reorder) -> build_slots -> qkv_gemm -> attn_out
// Shapes fixed: D=256, H=8, hd=32, W=2048, T=64, N=98304.
#define DD 256
#define TT 64
#define WW 2048

typedef unsigned short u16;
typedef __attribute__((ext_vector_type(8))) __bf16 bf8_t;   // MFMA A/B frag (4 VGPR)
typedef __attribute__((ext_vector_type(4))) float  f32x4;   // MFMA C/D frag

// XOR-swizzled [64 tok][256 col] u16 tile index (bank-conflict-free b128 col reads)
#define XSW(tok, col) ((tok) * 256 + ((col) ^ (((tok) & 7) << 3)))

__device__ __forceinline__ u16 f2bf(float x) {
  union { float f; unsigned u; } c; c.f = x;
  unsigned r = c.u + 0x7FFFu + ((c.u >> 16) & 1u);   // RNE
  return (u16)(r >> 16);
}
__device__ __forceinline__ int pack2(float a, float b) {
  return (int)((unsigned)f2bf(a) | ((unsigned)f2bf(b) << 16));
}

// Weight fragment layout: frag unit (kt, rt) = 16 out-rows x 32 k, stored as
// 64 lanes x 16B contiguous (1 KB). Lane l = g*16 + (row&15), elem j:
//   value = W[rt*16 + (l&15)][kt*32 + g*8 + j]
// This is exactly the MFMA A-frag (row=l&15) AND B-frag (col=l&15) register
// image used in all prior passing rounds -> every weight load is a coalesced
// dwordx4 at (frag_id*1024 + lane*16).
__global__ void prep_weights(const float* __restrict__ inw, const float* __restrict__ outw,
                             u16* __restrict__ fragW, u16* __restrict__ fragWo) {
  int i = blockIdx.x * blockDim.x + threadIdx.x;   // over 768*256
  int row = i >> 8, k = i & 255;
  int l  = (((k >> 3) & 3) << 4) | (row & 15);
  int j  = k & 7;
  int kt = k >> 5;
  if (i < 768 * 256)
    fragW[((size_t)(kt * 48 + (row >> 4)) * 64 + l) * 8 + j] = f2bf(inw[i]);
  if (i < 256 * 256)
    fragWo[((size_t)(kt * 16 + (row >> 4)) * 64 + l) * 8 + j] = f2bf(outw[i]);
}

__global__ void build_slots(const int* __restrict__ widx, const int* __restrict__ sidx,
                            int* __restrict__ wslots, int n) {
  int i = blockIdx.x * blockDim.x + threadIdx.x;
  if (i < n) wslots[widx[i] * TT + sidx[i]] = i;
}

// ---------------- K1: merged QKV projection ----------------
// grid N/64 = 1536 blocks, 768 threads = 12 waves:
//   waves 0-3: q cols 64wv..64wv+63  (A = Xqk rows, B = W frags)
//   waves 4-7: k cols                (inb packed q|k so inb[wv*64+..] works)
//   waves 8-11: v, swapped operands  (A = Wv frags rows=vdim, B = Xv^T cols=vox)
// K-loop: 8 steps of K=32, zero barriers, W frags prefetched 1 step ahead.
__global__ __launch_bounds__(768, 3) void qkv_gemm(
    const float* __restrict__ feat, const float* __restrict__ pos,
    const u16* __restrict__ fragW, const float* __restrict__ inb,
    const int* __restrict__ widx, const int* __restrict__ sidx,
    u16* __restrict__ qc, u16* __restrict__ kc, u16* __restrict__ vt) {

  __shared__ u16 Xqk[TT * 264];    // bf16(feat+pos), row stride 528 B
  __shared__ u16 Xv[TT * 264];     // bf16(feat)
  __shared__ u16 cb[TT * 520];     // q|k transpose-out buffer [64 vox][512+8]

  const int t    = threadIdx.x;
  const int wv   = t >> 6;         // 0..11
  const int lane = t & 63;
  const int g    = lane >> 4;
  const int l16  = lane & 15;
  const int m0   = blockIdx.x * 64;

  // ---- stage X once: threads 0-511, one voxel-seg each, emit BOTH buffers ----
  if (t < 512) {
    int vox = t >> 3, seg = t & 7;
    const float4* fp = (const float4*)(feat + (size_t)(m0 + vox) * DD + seg * 32);
    const float4* pp = (const float4*)(pos  + (size_t)(m0 + vox) * DD + seg * 32);
    float4 f[8], p[8];
#pragma unroll
    for (int j = 0; j < 8; ++j) { f[j] = fp[j]; p[j] = pp[j]; }
    const float* ff = (const float*)f;
    const float* pf = (const float*)p;
#pragma unroll
    for (int c = 0; c < 4; ++c) {
      union { u16 u[8]; bf8_t v; } rq, rv;
#pragma unroll
      for (int j = 0; j < 8; ++j) {
        float fv = ff[c * 8 + j];
        rq.u[j] = f2bf(fv + pf[c * 8 + j]);
        rv.u[j] = f2bf(fv);
      }
      *(bf8_t*)&Xqk[vox * 264 + seg * 32 + c * 8] = rq.v;
      *(bf8_t*)&Xv[vox * 264 + seg * 32 + c * 8]  = rv.v;
    }
  }
  __syncthreads();

  const bool isV   = (wv >= 8);
  const u16* Xsrc  = isV ? Xv : Xqk;
  const int rtbase = isV ? (32 + (wv - 8) * 4) : (wv * 4);

  const f32x4 zf = {0.f, 0.f, 0.f, 0.f};
  f32x4 acc[4][4];
#pragma unroll
  for (int mt = 0; mt < 4; ++mt)
#pragma unroll
    for (int nt = 0; nt < 4; ++nt) acc[mt][nt] = zf;

  // ---- K-loop: 8 steps, W frags coalesced + prefetched one step ahead ----
  bf8_t wf[4];
#pragma unroll
  for (int nt = 0; nt < 4; ++nt)
    wf[nt] = *(const bf8_t*)&fragW[((size_t)(rtbase + nt) * 64 + lane) * 8];

#pragma unroll
  for (int kt = 0; kt < 8; ++kt) {
    bf8_t wn[4];
    if (kt < 7) {
#pragma unroll
      for (int nt = 0; nt < 4; ++nt)
        wn[nt] = *(const bf8_t*)&fragW[((size_t)((kt + 1) * 48 + rtbase + nt) * 64 + lane) * 8];
    }
    bf8_t xa[4];
#pragma unroll
    for (int mt = 0; mt < 4; ++mt)
      xa[mt] = *(const bf8_t*)&Xsrc[(mt * 16 + l16) * 264 + kt * 32 + g * 8];

    if (!isV) {
#pragma unroll
      for (int nt = 0; nt < 4; ++nt)
#pragma unroll
        for (int mt = 0; mt < 4; ++mt)
          acc[mt][nt] = __builtin_amdgcn_mfma_f32_16x16x32_bf16(xa[mt], wf[nt], acc[mt][nt], 0, 0, 0);
    } else {
#pragma unroll
      for (int mt = 0; mt < 4; ++mt)
#pragma unroll
        for (int nt = 0; nt < 4; ++nt)
          acc[mt][nt] = __builtin_amdgcn_mfma_f32_16x16x32_bf16(wf[mt], xa[nt], acc[mt][nt], 0, 0, 0);
    }
    if (kt < 7) {
#pragma unroll
      for (int nt = 0; nt < 4; ++nt) wf[nt] = wn[nt];
    }
  }

  // ---- epilogue ----
  if (!isV) {
    // q|k: C[vox][col] -> cb, then coalesced copy out
#pragma unroll
    for (int nt = 0; nt < 4; ++nt) {
      float b = inb[wv * 64 + nt * 16 + l16];     // packed q|k biases
#pragma unroll
      for (int mt = 0; mt < 4; ++mt)
#pragma unroll
        for (int r = 0; r < 4; ++r)
          cb[(mt * 16 + 4 * g + r) * 520 + wv * 64 + nt * 16 + l16] = f2bf(acc[mt][nt][r] + b);
    }
  } else {
    // v: C[vdim][vox] -> direct transposed window scatter vt[w][vdim][slot]
    // pad slots never written -> finite garbage x exactly-0 attention weight
#pragma unroll
    for (int nt = 0; nt < 4; ++nt) {
      int vx = m0 + nt * 16 + l16;
      size_t bw_ = (size_t)widx[vx] * (DD * TT) + sidx[vx];
#pragma unroll
      for (int mt = 0; mt < 4; ++mt)
#pragma unroll
        for (int r = 0; r < 4; ++r) {
          int vd = (wv - 8) * 64 + mt * 16 + 4 * g + r;
          vt[bw_ + (size_t)vd * TT] = f2bf(acc[mt][nt][r] + inb[512 + vd]);
        }
    }
  }
  __syncthreads();

  // coalesced copy cb -> qc/kc (4096 x 16B chunks)
#pragma unroll
  for (int r = 0; r < 6; ++r) {
    int c = r * 768 + t;
    if (c < 4096) {
      int vox = c >> 6, col = (c & 63) * 8;
      bf8_t v = *(const bf8_t*)&cb[vox * 520 + col];
      if (col < 256) *(bf8_t*)&qc[(size_t)(m0 + vox) * DD + col] = v;
      else           *(bf8_t*)&kc[(size_t)(m0 + vox) * DD + col - 256] = v;
    }
  }
}

// ---------------- K2: attention + out_proj ----------------
// grid 2048: block = window, 256 thr = 4 waves, wave wv does heads {2wv, 2wv+1}.
// k/q frags gathered from global by slot table; vt frags contiguous;
// out_proj weights from fragWo (coalesced) with one-kk-ahead prefetch.
__global__ __launch_bounds__(256, 4) void attn_out(
    const u16* __restrict__ qc, const u16* __restrict__ kc, const u16* __restrict__ vt,
    const u16* __restrict__ fragWo, const float* __restrict__ outb,
    const int* __restrict__ wslots, float* __restrict__ out) {

  __shared__ int tl[TT];
  __shared__ u16 ab[TT * 256];     // aout [64 tok][256], XSW-swizzled

  const int t    = threadIdx.x;
  const int wv   = t >> 6;
  const int lane = t & 63;
  const int g    = lane >> 4;
  const int l16  = lane & 15;
  const int w    = blockIdx.x;

  if (t < TT) tl[t] = wslots[w * TT + t];
  __syncthreads();

  const f32x4 zf = {0.f, 0.f, 0.f, 0.f};

  bool vm[4][4];
#pragma unroll
  for (int mt = 0; mt < 4; ++mt)
#pragma unroll
    for (int r = 0; r < 4; ++r) vm[mt][r] = (tl[mt * 16 + 4 * g + r] >= 0);

#pragma unroll 1
  for (int hh = 0; hh < 2; ++hh) {
    const int h = wv * 2 + hh;

    // ---- S^T = K · Q^T ----
    bf8_t akf[4], bqf[4];
#pragma unroll
    for (int mt = 0; mt < 4; ++mt) {
      int row = tl[mt * 16 + l16]; row = row < 0 ? 0 : row;
      akf[mt] = *(const bf8_t*)&kc[(size_t)row * DD + h * 32 + g * 8];
    }
#pragma unroll
    for (int nt = 0; nt < 4; ++nt) {
      int row = tl[nt * 16 + l16]; row = row < 0 ? 0 : row;
      bqf[nt] = *(const bf8_t*)&qc[(size_t)row * DD + h * 32 + g * 8];
    }

    f32x4 sa[4][4];
#pragma unroll
    for (int mt = 0; mt < 4; ++mt)
#pragma unroll
      for (int nt = 0; nt < 4; ++nt)
        sa[mt][nt] = __builtin_amdgcn_mfma_f32_16x16x32_bf16(akf[mt], bqf[nt], zf, 0, 0, 0);

    // ---- masked softmax along tok (q-row lane-local across 4 groups) ----
    const float scale = 0.17677669529663687f;  // 1/sqrt(32)
    int pk[4][4][2];
#pragma unroll
    for (int nt = 0; nt < 4; ++nt) {
      float sv[4][4];
      float m = -3e38f;
#pragma unroll
      for (int mt = 0; mt < 4; ++mt)
#pragma unroll
        for (int r = 0; r < 4; ++r) {
          float s = vm[mt][r] ? sa[mt][nt][r] * scale : -3e38f;
          sv[mt][r] = s;
          m = fmaxf(m, s);
        }
      m = fmaxf(m, __shfl_xor(m, 16, 64));
      m = fmaxf(m, __shfl_xor(m, 32, 64));
      float sum = 0.f;
#pragma unroll
      for (int mt = 0; mt < 4; ++mt)
#pragma unroll
        for (int r = 0; r < 4; ++r) {
          float pv = vm[mt][r] ? __expf(sv[mt][r] - m) : 0.f;
          sv[mt][r] = pv;
          sum += pv;
        }
      sum += __shfl_xor(sum, 16, 64);
      sum += __shfl_xor(sum, 32, 64);
      float inv = sum > 0.f ? 1.f / sum : 0.f;
#pragma unroll
      for (int mt = 0; mt < 4; ++mt)
#pragma unroll
        for (int rp = 0; rp < 2; ++rp)
          pk[mt][nt][rp] = pack2(sv[mt][2 * rp] * inv, sv[mt][2 * rp + 1] * inv);
    }

    // ---- PV: out^T = V^T · P^T ----
    bf8_t avf[2][2];
#pragma unroll
    for (int md = 0; md < 2; ++md)
#pragma unroll
      for (int kk = 0; kk < 2; ++kk)
        avf[md][kk] = *(const bf8_t*)&vt[(size_t)w * (DD * TT) +
                                        (size_t)(h * 32 + md * 16 + l16) * TT + kk * 32 + g * 8];

    f32x4 oa[2][4];
#pragma unroll
    for (int md = 0; md < 2; ++md)
#pragma unroll
      for (int nt = 0; nt < 4; ++nt) oa[md][nt] = zf;

#pragma unroll
    for (int kk = 0; kk < 2; ++kk) {
#pragma unroll
      for (int nt = 0; nt < 4; ++nt) {
        union { int wd[4]; bf8_t v; } bu;
#pragma unroll
        for (int wd = 0; wd < 4; ++wd) {
          int src = l16 + 16 * (2 * (g & 1) + (wd >> 1));
          int lo = __shfl(pk[2 * kk + 0][nt][wd & 1], src, 64);
          int hi = __shfl(pk[2 * kk + 1][nt][wd & 1], src, 64);
          bu.wd[wd] = (g & 2) ? hi : lo;
        }
#pragma unroll
        for (int md = 0; md < 2; ++md)
          oa[md][nt] = __builtin_amdgcn_mfma_f32_16x16x32_bf16(avf[md][kk], bu.v, oa[md][nt], 0, 0, 0);
      }
    }

    // ---- aout -> ab (own head's 32-col slice) ----
#pragma unroll
    for (int md = 0; md < 2; ++md)
#pragma unroll
      for (int nt = 0; nt < 4; ++nt) {
        int w0 = pack2(oa[md][nt][0], oa[md][nt][1]);
        int w1 = pack2(oa[md][nt][2], oa[md][nt][3]);
        *(int2*)&ab[XSW(nt * 16 + l16, h * 32 + md * 16 + 4 * g)] = make_int2(w0, w1);
      }
  }
  __syncthreads();     // aout all-visible

  // ---- out_proj: wave wv -> cols wv*64..+63; fragWo coalesced, prefetched ----
  f32x4 fa[4][4];
#pragma unroll
  for (int mt = 0; mt < 4; ++mt)
#pragma unroll
    for (int nt = 0; nt < 4; ++nt) fa[mt][nt] = zf;

  bf8_t bwf[4];
#pragma unroll
  for (int nt = 0; nt < 4; ++nt)
    bwf[nt] = *(const bf8_t*)&fragWo[((size_t)(wv * 4 + nt) * 64 + lane) * 8];

#pragma unroll
  for (int kk = 0; kk < 8; ++kk) {
    bf8_t bwn[4];
    if (kk < 7) {
#pragma unroll
      for (int nt = 0; nt < 4; ++nt)
        bwn[nt] = *(const bf8_t*)&fragWo[((size_t)((kk + 1) * 16 + wv * 4 + nt) * 64 + lane) * 8];
    }
    bf8_t aa[4];
#pragma unroll
    for (int mt = 0; mt < 4; ++mt)
      aa[mt] = *(const bf8_t*)&ab[XSW(mt * 16 + l16, kk * 32 + g * 8)];
#pragma unroll
    for (int nt = 0; nt < 4; ++nt)
#pragma unroll
      for (int mt = 0; mt < 4; ++mt)
        fa[mt][nt] = __builtin_amdgcn_mfma_f32_16x16x32_bf16(aa[mt], bwf[nt], fa[mt][nt], 0, 0, 0);
    if (kk < 7) {
#pragma unroll
      for (int nt = 0; nt < 4; ++nt) bwf[nt] = bwn[nt];
    }
  }

#pragma unroll
  for (int nt = 0; nt < 4; ++nt) {
    float ob = outb[wv * 64 + nt * 16 + l16];
#pragma unroll
    for (int mt = 0; mt < 4; ++mt)
#pragma unroll
      for (int r = 0; r < 4; ++r) {
        int row = tl[mt * 16 + 4 * g + r];
        if (row >= 0)
          out[(size_t)row * DD + wv * 64 + nt * 16 + l16] = fa[mt][nt][r] + ob;
      }
  }
}

extern "C" void kernel_launch(void* const* d_in, const int* in_sizes, int n_in,
                              void* d_out, int out_size, void* d_ws, size_t ws_size,
                              hipStream_t stream) {
  (void)n_in; (void)out_size; (void)ws_size;
  const float* feat = (const float*)d_in[0];
  const float* pos  = (const float*)d_in[1];
  const float* inw  = (const float*)d_in[2];
  const float* inb  = (const float*)d_in[3];
  const float* outw = (const float*)d_in[4];
  const float* outb = (const float*)d_in[5];
  const int*   widx = (const int*)d_in[6];
  const int*   sidx = (const int*)d_in[7];
  const int N = in_sizes[0] / DD;

  char* ws = (char*)d_ws;
  u16* fragW  = (u16*)ws;                                    // 393216 B
  u16* fragWo = (u16*)(ws + 393216);                         // 131072 B
  int* wslots = (int*)(ws + 393216 + 131072);                // 524288 B
  size_t off  = 1048576;
  u16* qc = (u16*)(ws + off); off += (size_t)N * DD * 2;     // 50.3 MB
  u16* kc = (u16*)(ws + off); off += (size_t)N * DD * 2;     // 50.3 MB
  u16* vt = (u16*)(ws + off);                                // 67.1 MB

  hipMemsetAsync(wslots, 0xFF, WW * TT * sizeof(int), stream);
  prep_weights<<<768, 256, 0, stream>>>(inw, outw, fragW, fragWo);
  build_slots<<<(N + 255) / 256, 256, 0, stream>>>(widx, sidx, wslots, N);
  qkv_gemm<<<N / 64, 768, 0, stream>>>(feat, pos, fragW, inb, widx, sidx, qc, kc, vt);
  attn_out<<<WW, 256, 0, stream>>>(qc, kc, vt, fragWo, outb, wslots, (float*)d_out);
}

// Round 8
// 260.414 us; speedup vs baseline: 1.9992x; 1.1980x over previous
//
#include <hip/hip_runtime.h>

// WindowAttention, MI355X (gfx950). Pipeline:
//   prep_weights (frag-reorder) -> build_slots -> qkv_gemm (pass-split) -> attn_out
// Shapes fixed: D=256, H=8, hd=32, W=2048, T=64, N=98304.
#define DD 256
#define TT 64
#define WW 2048

typedef unsigned short u16;
typedef __attribute__((ext_vector_type(8))) __bf16 bf8_t;   // MFMA A/B frag (4 VGPR)
typedef __attribute__((ext_vector_type(4))) float  f32x4;   // MFMA C/D frag

// XOR-swizzled [64 tok][256 col] u16 tile index (bank-conflict-free b128 col reads)
#define XSW(tok, col) ((tok) * 256 + ((col) ^ (((tok) & 7) << 3)))

__device__ __forceinline__ u16 f2bf(float x) {
  union { float f; unsigned u; } c; c.f = x;
  unsigned r = c.u + 0x7FFFu + ((c.u >> 16) & 1u);   // RNE
  return (u16)(r >> 16);
}
__device__ __forceinline__ int pack2(float a, float b) {
  return (int)((unsigned)f2bf(a) | ((unsigned)f2bf(b) << 16));
}

// Weight fragment layout: frag unit (kt, rt) = 16 out-rows x 32 k, stored as
// 64 lanes x 16B contiguous (1 KB). Lane l = g*16 + (row&15), elem j:
//   value = W[rt*16 + (l&15)][kt*32 + g*8 + j]
// Same image serves MFMA A-frag (row=l&15) and B-frag (col=l&15) -> every
// weight load is a coalesced dwordx4 at (frag_id*1024 + lane*16).
__global__ void prep_weights(const float* __restrict__ inw, const float* __restrict__ outw,
                             u16* __restrict__ fragW, u16* __restrict__ fragWo) {
  int i = blockIdx.x * blockDim.x + threadIdx.x;   // over 768*256
  int row = i >> 8, k = i & 255;
  int l  = (((k >> 3) & 3) << 4) | (row & 15);
  int j  = k & 7;
  int kt = k >> 5;
  if (i < 768 * 256)
    fragW[((size_t)(kt * 48 + (row >> 4)) * 64 + l) * 8 + j] = f2bf(inw[i]);
  if (i < 256 * 256)
    fragWo[((size_t)(kt * 16 + (row >> 4)) * 64 + l) * 8 + j] = f2bf(outw[i]);
}

__global__ void build_slots(const int* __restrict__ widx, const int* __restrict__ sidx,
                            int* __restrict__ wslots, int n) {
  int i = blockIdx.x * blockDim.x + threadIdx.x;
  if (i < n) wslots[widx[i] * TT + sidx[i]] = i;
}

// ---------------- K1: QKV projection, pass-split ----------------
// grid (3, N/64): x = pass (0=q,1=k,2=v) so the 3 passes of an M-tile are
// co-resident (feat/pos re-reads L2-hit); y = 64-voxel M-tile.
// 256 threads = 4 waves; wave wv owns a 64-col (p<2) / 64-row (v) slice.
// One 34 KB LDS buffer: X during the K-loop, q/k transpose buffer after.
// K-loop: 8 steps of K=32, zero barriers, frag weights prefetched 1 ahead.
__global__ __launch_bounds__(256, 3) void qkv_gemm(
    const float* __restrict__ feat, const float* __restrict__ pos,
    const u16* __restrict__ fragW, const float* __restrict__ inb,
    const int* __restrict__ widx, const int* __restrict__ sidx,
    u16* __restrict__ qc, u16* __restrict__ kc, u16* __restrict__ vt) {

  __shared__ u16 XB[TT * 264];     // [64][264] u16: X, then q/k epilogue buffer

  const int t    = threadIdx.x;
  const int wv   = t >> 6;         // 0..3
  const int lane = t & 63;
  const int g    = lane >> 4;
  const int l16  = lane & 15;
  const int p    = blockIdx.x;     // 0=q 1=k 2=v
  const int m0   = blockIdx.y * 64;

  // ---- stage X: thread -> voxel t>>2, 64-dim slice (t&3)*64, two 32-dim bursts ----
  {
    const int vox  = t >> 2;
    const int dblk = (t & 3) * 64;
#pragma unroll
    for (int c2 = 0; c2 < 2; ++c2) {
      const int d0 = dblk + c2 * 32;
      const float4* fp = (const float4*)(feat + (size_t)(m0 + vox) * DD + d0);
      float4 f[8];
#pragma unroll
      for (int j = 0; j < 8; ++j) f[j] = fp[j];
      const float* ff = (const float*)f;
      if (p < 2) {
        const float4* pp = (const float4*)(pos + (size_t)(m0 + vox) * DD + d0);
        float4 q[8];
#pragma unroll
        for (int j = 0; j < 8; ++j) q[j] = pp[j];
        const float* pf = (const float*)q;
#pragma unroll
        for (int c = 0; c < 4; ++c) {
          union { u16 u[8]; bf8_t v; } r;
#pragma unroll
          for (int j = 0; j < 8; ++j) r.u[j] = f2bf(ff[c * 8 + j] + pf[c * 8 + j]);
          *(bf8_t*)&XB[vox * 264 + d0 + c * 8] = r.v;
        }
      } else {
#pragma unroll
        for (int c = 0; c < 4; ++c) {
          union { u16 u[8]; bf8_t v; } r;
#pragma unroll
          for (int j = 0; j < 8; ++j) r.u[j] = f2bf(ff[c * 8 + j]);
          *(bf8_t*)&XB[vox * 264 + d0 + c * 8] = r.v;
        }
      }
    }
  }
  __syncthreads();

  const int rtb = p * 16 + wv * 4;   // frag row-tile base for this wave

  const f32x4 zf = {0.f, 0.f, 0.f, 0.f};
  f32x4 acc[4][4];
#pragma unroll
  for (int mt = 0; mt < 4; ++mt)
#pragma unroll
    for (int nt = 0; nt < 4; ++nt) acc[mt][nt] = zf;

  // ---- K-loop: 8 steps, coalesced frag weights prefetched one step ahead ----
  bf8_t wf[4];
#pragma unroll
  for (int nt = 0; nt < 4; ++nt)
    wf[nt] = *(const bf8_t*)&fragW[((size_t)(rtb + nt) * 64 + lane) * 8];

#pragma unroll
  for (int kt = 0; kt < 8; ++kt) {
    bf8_t wn[4];
    if (kt < 7) {
#pragma unroll
      for (int nt = 0; nt < 4; ++nt)
        wn[nt] = *(const bf8_t*)&fragW[((size_t)((kt + 1) * 48 + rtb + nt) * 64 + lane) * 8];
    }
    bf8_t xa[4];
#pragma unroll
    for (int mt = 0; mt < 4; ++mt)
      xa[mt] = *(const bf8_t*)&XB[(mt * 16 + l16) * 264 + kt * 32 + g * 8];

    if (p < 2) {
#pragma unroll
      for (int nt = 0; nt < 4; ++nt)
#pragma unroll
        for (int mt = 0; mt < 4; ++mt)
          acc[mt][nt] = __builtin_amdgcn_mfma_f32_16x16x32_bf16(xa[mt], wf[nt], acc[mt][nt], 0, 0, 0);
    } else {
#pragma unroll
      for (int mt = 0; mt < 4; ++mt)
#pragma unroll
        for (int nt = 0; nt < 4; ++nt)
          acc[mt][nt] = __builtin_amdgcn_mfma_f32_16x16x32_bf16(wf[mt], xa[nt], acc[mt][nt], 0, 0, 0);
    }
    if (kt < 7) {
#pragma unroll
      for (int nt = 0; nt < 4; ++nt) wf[nt] = wn[nt];
    }
  }

  // ---- epilogue ----
  if (p < 2) {
    __syncthreads();   // all X reads done -> XB reusable as transpose buffer
    // bias + C[vox][col] -> XB, then coalesced copy out
#pragma unroll
    for (int nt = 0; nt < 4; ++nt) {
      float b = inb[p * 256 + wv * 64 + nt * 16 + l16];
#pragma unroll
      for (int mt = 0; mt < 4; ++mt)
#pragma unroll
        for (int r = 0; r < 4; ++r)
          XB[(mt * 16 + 4 * g + r) * 264 + wv * 64 + nt * 16 + l16] = f2bf(acc[mt][nt][r] + b);
    }
    __syncthreads();
    u16* dst = p ? kc : qc;
#pragma unroll
    for (int it = 0; it < 8; ++it) {
      int i = it * 256 + t;
      int row = i >> 5, col = (i & 31) * 8;
      *(bf8_t*)&dst[(size_t)(m0 + row) * DD + col] = *(const bf8_t*)&XB[row * 264 + col];
    }
  } else {
    // v: C[vdim][vox] -> direct transposed window scatter vt[w][vdim][slot]
    // (R5-verified; pad slots never written -> finite garbage x exactly-0 weight)
#pragma unroll
    for (int nt = 0; nt < 4; ++nt) {
      int vx = m0 + nt * 16 + l16;
      size_t bw_ = (size_t)widx[vx] * (DD * TT) + sidx[vx];
#pragma unroll
      for (int mt = 0; mt < 4; ++mt)
#pragma unroll
        for (int r = 0; r < 4; ++r) {
          int vd = wv * 64 + mt * 16 + 4 * g + r;
          vt[bw_ + (size_t)vd * TT] = f2bf(acc[mt][nt][r] + inb[512 + vd]);
        }
    }
  }
}

// ---------------- K2: attention + out_proj (unchanged, R7-passing) ----------------
// grid 2048: block = window, 256 thr = 4 waves, wave wv does heads {2wv, 2wv+1}.
__global__ __launch_bounds__(256, 4) void attn_out(
    const u16* __restrict__ qc, const u16* __restrict__ kc, const u16* __restrict__ vt,
    const u16* __restrict__ fragWo, const float* __restrict__ outb,
    const int* __restrict__ wslots, float* __restrict__ out) {

  __shared__ int tl[TT];
  __shared__ u16 ab[TT * 256];     // aout [64 tok][256], XSW-swizzled

  const int t    = threadIdx.x;
  const int wv   = t >> 6;
  const int lane = t & 63;
  const int g    = lane >> 4;
  const int l16  = lane & 15;
  const int w    = blockIdx.x;

  if (t < TT) tl[t] = wslots[w * TT + t];
  __syncthreads();

  const f32x4 zf = {0.f, 0.f, 0.f, 0.f};

  bool vm[4][4];
#pragma unroll
  for (int mt = 0; mt < 4; ++mt)
#pragma unroll
    for (int r = 0; r < 4; ++r) vm[mt][r] = (tl[mt * 16 + 4 * g + r] >= 0);

#pragma unroll 1
  for (int hh = 0; hh < 2; ++hh) {
    const int h = wv * 2 + hh;

    // ---- S^T = K · Q^T ----
    bf8_t akf[4], bqf[4];
#pragma unroll
    for (int mt = 0; mt < 4; ++mt) {
      int row = tl[mt * 16 + l16]; row = row < 0 ? 0 : row;
      akf[mt] = *(const bf8_t*)&kc[(size_t)row * DD + h * 32 + g * 8];
    }
#pragma unroll
    for (int nt = 0; nt < 4; ++nt) {
      int row = tl[nt * 16 + l16]; row = row < 0 ? 0 : row;
      bqf[nt] = *(const bf8_t*)&qc[(size_t)row * DD + h * 32 + g * 8];
    }

    f32x4 sa[4][4];
#pragma unroll
    for (int mt = 0; mt < 4; ++mt)
#pragma unroll
      for (int nt = 0; nt < 4; ++nt)
        sa[mt][nt] = __builtin_amdgcn_mfma_f32_16x16x32_bf16(akf[mt], bqf[nt], zf, 0, 0, 0);

    // ---- masked softmax along tok (q-row lane-local across 4 groups) ----
    const float scale = 0.17677669529663687f;  // 1/sqrt(32)
    int pk[4][4][2];
#pragma unroll
    for (int nt = 0; nt < 4; ++nt) {
      float sv[4][4];
      float m = -3e38f;
#pragma unroll
      for (int mt = 0; mt < 4; ++mt)
#pragma unroll
        for (int r = 0; r < 4; ++r) {
          float s = vm[mt][r] ? sa[mt][nt][r] * scale : -3e38f;
          sv[mt][r] = s;
          m = fmaxf(m, s);
        }
      m = fmaxf(m, __shfl_xor(m, 16, 64));
      m = fmaxf(m, __shfl_xor(m, 32, 64));
      float sum = 0.f;
#pragma unroll
      for (int mt = 0; mt < 4; ++mt)
#pragma unroll
        for (int r = 0; r < 4; ++r) {
          float pv = vm[mt][r] ? __expf(sv[mt][r] - m) : 0.f;
          sv[mt][r] = pv;
          sum += pv;
        }
      sum += __shfl_xor(sum, 16, 64);
      sum += __shfl_xor(sum, 32, 64);
      float inv = sum > 0.f ? 1.f / sum : 0.f;
#pragma unroll
      for (int mt = 0; mt < 4; ++mt)
#pragma unroll
        for (int rp = 0; rp < 2; ++rp)
          pk[mt][nt][rp] = pack2(sv[mt][2 * rp] * inv, sv[mt][2 * rp + 1] * inv);
    }

    // ---- PV: out^T = V^T · P^T ----
    bf8_t avf[2][2];
#pragma unroll
    for (int md = 0; md < 2; ++md)
#pragma unroll
      for (int kk = 0; kk < 2; ++kk)
        avf[md][kk] = *(const bf8_t*)&vt[(size_t)w * (DD * TT) +
                                        (size_t)(h * 32 + md * 16 + l16) * TT + kk * 32 + g * 8];

    f32x4 oa[2][4];
#pragma unroll
    for (int md = 0; md < 2; ++md)
#pragma unroll
      for (int nt = 0; nt < 4; ++nt) oa[md][nt] = zf;

#pragma unroll
    for (int kk = 0; kk < 2; ++kk) {
#pragma unroll
      for (int nt = 0; nt < 4; ++nt) {
        union { int wd[4]; bf8_t v; } bu;
#pragma unroll
        for (int wd = 0; wd < 4; ++wd) {
          int src = l16 + 16 * (2 * (g & 1) + (wd >> 1));
          int lo = __shfl(pk[2 * kk + 0][nt][wd & 1], src, 64);
          int hi = __shfl(pk[2 * kk + 1][nt][wd & 1], src, 64);
          bu.wd[wd] = (g & 2) ? hi : lo;
        }
#pragma unroll
        for (int md = 0; md < 2; ++md)
          oa[md][nt] = __builtin_amdgcn_mfma_f32_16x16x32_bf16(avf[md][kk], bu.v, oa[md][nt], 0, 0, 0);
      }
    }

    // ---- aout -> ab (own head's 32-col slice) ----
#pragma unroll
    for (int md = 0; md < 2; ++md)
#pragma unroll
      for (int nt = 0; nt < 4; ++nt) {
        int w0 = pack2(oa[md][nt][0], oa[md][nt][1]);
        int w1 = pack2(oa[md][nt][2], oa[md][nt][3]);
        *(int2*)&ab[XSW(nt * 16 + l16, h * 32 + md * 16 + 4 * g)] = make_int2(w0, w1);
      }
  }
  __syncthreads();     // aout all-visible

  // ---- out_proj: wave wv -> cols wv*64..+63; fragWo coalesced, prefetched ----
  f32x4 fa[4][4];
#pragma unroll
  for (int mt = 0; mt < 4; ++mt)
#pragma unroll
    for (int nt = 0; nt < 4; ++nt) fa[mt][nt] = zf;

  bf8_t bwf[4];
#pragma unroll
  for (int nt = 0; nt < 4; ++nt)
    bwf[nt] = *(const bf8_t*)&fragWo[((size_t)(wv * 4 + nt) * 64 + lane) * 8];

#pragma unroll
  for (int kk = 0; kk < 8; ++kk) {
    bf8_t bwn[4];
    if (kk < 7) {
#pragma unroll
      for (int nt = 0; nt < 4; ++nt)
        bwn[nt] = *(const bf8_t*)&fragWo[((size_t)((kk + 1) * 16 + wv * 4 + nt) * 64 + lane) * 8];
    }
    bf8_t aa[4];
#pragma unroll
    for (int mt = 0; mt < 4; ++mt)
      aa[mt] = *(const bf8_t*)&ab[XSW(mt * 16 + l16, kk * 32 + g * 8)];
#pragma unroll
    for (int nt = 0; nt < 4; ++nt)
#pragma unroll
      for (int mt = 0; mt < 4; ++mt)
        fa[mt][nt] = __builtin_amdgcn_mfma_f32_16x16x32_bf16(aa[mt], bwf[nt], fa[mt][nt], 0, 0, 0);
    if (kk < 7) {
#pragma unroll
      for (int nt = 0; nt < 4; ++nt) bwf[nt] = bwn[nt];
    }
  }

#pragma unroll
  for (int nt = 0; nt < 4; ++nt) {
    float ob = outb[wv * 64 + nt * 16 + l16];
#pragma unroll
    for (int mt = 0; mt < 4; ++mt)
#pragma unroll
      for (int r = 0; r < 4; ++r) {
        int row = tl[mt * 16 + 4 * g + r];
        if (row >= 0)
          out[(size_t)row * DD + wv * 64 + nt * 16 + l16] = fa[mt][nt][r] + ob;
      }
  }
}

extern "C" void kernel_launch(void* const* d_in, const int* in_sizes, int n_in,
                              void* d_out, int out_size, void* d_ws, size_t ws_size,
                              hipStream_t stream) {
  (void)n_in; (void)out_size; (void)ws_size;
  const float* feat = (const float*)d_in[0];
  const float* pos  = (const float*)d_in[1];
  const float* inw  = (const float*)d_in[2];
  const float* inb  = (const float*)d_in[3];
  const float* outw = (const float*)d_in[4];
  const float* outb = (const float*)d_in[5];
  const int*   widx = (const int*)d_in[6];
  const int*   sidx = (const int*)d_in[7];
  const int N = in_sizes[0] / DD;

  char* ws = (char*)d_ws;
  u16* fragW  = (u16*)ws;                                    // 393216 B
  u16* fragWo = (u16*)(ws + 393216);                         // 131072 B
  int* wslots = (int*)(ws + 393216 + 131072);                // 524288 B
  size_t off  = 1048576;
  u16* qc = (u16*)(ws + off); off += (size_t)N * DD * 2;     // 50.3 MB
  u16* kc = (u16*)(ws + off); off += (size_t)N * DD * 2;     // 50.3 MB
  u16* vt = (u16*)(ws + off);                                // 67.1 MB

  hipMemsetAsync(wslots, 0xFF, WW * TT * sizeof(int), stream);
  prep_weights<<<768, 256, 0, stream>>>(inw, outw, fragW, fragWo);
  build_slots<<<(N + 255) / 256, 256, 0, stream>>>(widx, sidx, wslots, N);
  qkv_gemm<<<dim3(3, N / 64), 256, 0, stream>>>(feat, pos, fragW, inb, widx, sidx, qc, kc, vt);
  attn_out<<<WW, 256, 0, stream>>>(qc, kc, vt, fragWo, outb, wslots, (float*)d_out);
}